// Round 15
// baseline (399.798 us; speedup 1.0000x reference)
//
#include <hip/hip_runtime.h>
#include <hip/hip_bf16.h>
#include <math.h>

// ---------------------------------------------------------------------------
// TransformerBlock on MI355X (gfx950).
// B=2, N=2048 (M=4096 tokens), DIM=1024, HEADS=16, HEAD_DIM=64, HIDDEN=4096.
// R23->R24: bf16 split-K partials. Profile is flat/latency-bound; remaining
// lever is traffic: fp32 partials moved ~130MB across O-proj/FF2 writes and
// the two reduces. Partials are single-rounded full-fp32 MFMA sums -> bf16
// adds ~1-3e-3 abs error (current absmax 0.03125) and halves that traffic
// (~65MB ~= -10us). Alias fix: pa -> vtg region (was qb, which x1f
// overwrites mid-kernel in reduce_ln: cross-thread byte-range race);
// p0 -> ao region (dead after O-proj); p1 unchanged.
// attn keeps R23's conflict-free K/V segment layout (passed, attn <63us).
// ---------------------------------------------------------------------------

typedef unsigned short ushort_t;
typedef short short8 __attribute__((ext_vector_type(8)));
typedef float f32x4 __attribute__((ext_vector_type(4)));

#define TOKENS 4096
#define SEQ    2048
#define DIMC   1024
#define HID    4096

__device__ __forceinline__ float bf2f(ushort_t u) {
    union { float f; unsigned int u; } c; c.u = ((unsigned int)u) << 16; return c.f;
}
__device__ __forceinline__ ushort_t f2bf(float f) {
    union { float f; unsigned int u; } c; c.f = f;
    unsigned int u = c.u;
    unsigned int r = u + 0x7fffu + ((u >> 16) & 1u);   // round-nearest-even
    return (ushort_t)(r >> 16);
}
// tanh-approx GELU (max |err| vs exact ~1e-3; cheap: one __expf)
__device__ __forceinline__ float gelu_f(float x) {
    const float y = 0.79788456080286536f * (x + 0.044715f * x * x * x);
    const float t = __expf(-2.0f * fabsf(y));          // in (0,1]
    const float th = (1.0f - t) / (1.0f + t);          // tanh(|y|)
    return 0.5f * x * (1.0f + copysignf(th, y));
}
__device__ __forceinline__ float load_elem(const void* p, size_t i, int isbf) {
    return isbf ? bf2f(((const ushort_t*)p)[i]) : ((const float*)p)[i];
}

// ---------------------------------------------------------------------------
// Detect input dtype. flag[0] = 1 (bf16) / 0 (fp32); flag[1] = constant 1.
// ---------------------------------------------------------------------------
__global__ __launch_bounds__(256) void detect_dtype(
    const ushort_t* __restrict__ x, int* __restrict__ flag)
{
    __shared__ int bad;
    if (threadIdx.x == 0) bad = 0;
    __syncthreads();
    for (int i = threadIdx.x; i < 4096; i += 256) {
        float v = bf2f(x[i]);
        if (!(fabsf(v) <= 1e6f)) bad = 1;   // catches huge AND NaN
    }
    __syncthreads();
    if (threadIdx.x == 0) { flag[0] = (bad == 0) ? 1 : 0; flag[1] = 1; }
}

// ---------------------------------------------------------------------------
// All 6 weight transposes in ONE flat-grid dispatch.
// tiles: ids 0..4095 -> Wq/Wk/Wv/Wo (1024 tiles each, 32x32 grid),
//        4096..8191 -> W1 (1024x4096: 128x32), 8192..12287 -> W2 (4096x1024: 32x128).
// ---------------------------------------------------------------------------
__global__ __launch_bounds__(256) void transpose_w_all(
    const void* __restrict__ Wq, const void* __restrict__ Wk,
    const void* __restrict__ Wv, const void* __restrict__ Wo,
    const void* __restrict__ W1, const void* __restrict__ W2,
    ushort_t* __restrict__ wsq, ushort_t* __restrict__ w1t,
    ushort_t* __restrict__ w2t, const int* __restrict__ flag)
{
    __shared__ ushort_t tile[32][33];
    const int isbf = *flag;
    const int id = blockIdx.x;
    const void* in; ushort_t* out; int K, N, bx, by;
    if (id < 4096) {
        const int z = id >> 10, t = id & 1023;
        in = z == 0 ? Wq : (z == 1 ? Wk : (z == 2 ? Wv : Wo));
        out = wsq + (size_t)z * DIMC * DIMC;
        K = DIMC; N = DIMC; bx = t & 31; by = t >> 5;
    } else if (id < 8192) {
        const int t = id - 4096;
        in = W1; out = w1t; K = DIMC; N = HID;
        bx = t & 127; by = t >> 7;
    } else {
        const int t = id - 8192;
        in = W2; out = w2t; K = HID; N = DIMC;
        bx = t & 31; by = t >> 5;
    }
    const int kb = by * 32, nb = bx * 32;
    const int tx = threadIdx.x & 31, ty = threadIdx.x >> 5;
    for (int i = 0; i < 4; i++) {
        int k = kb + ty + i * 8;
        tile[ty + i * 8][tx] = f2bf(load_elem(in, (size_t)k * N + nb + tx, isbf));
    }
    __syncthreads();
    for (int i = 0; i < 4; i++) {
        int n = nb + ty + i * 8;
        out[(size_t)n * K + kb + tx] = tile[tx][ty + i * 8];
    }
}

// ---------------------------------------------------------------------------
// LayerNorm over last dim (1024). One block per token, 256 threads.
// INMODE 0: input dtype per flag (raw x). INMODE 1: input always fp32 (ws).
// ---------------------------------------------------------------------------
template<int INMODE>
__global__ __launch_bounds__(256) void ln_kernel(
    const void* __restrict__ in, const void* __restrict__ g,
    const void* __restrict__ b, const int* __restrict__ flag,
    ushort_t* __restrict__ out)
{
    const int isbf = *flag;
    const int t = blockIdx.x;
    const int tid = threadIdx.x;
    const size_t base = (size_t)t * DIMC;
    float v[4];
    for (int i = 0; i < 4; i++) {
        int idx = tid + i * 256;
        v[i] = (INMODE == 1) ? ((const float*)in)[base + idx]
                             : load_elem(in, base + idx, isbf);
    }
    float s  = v[0] + v[1] + v[2] + v[3];
    float s2 = v[0]*v[0] + v[1]*v[1] + v[2]*v[2] + v[3]*v[3];
    for (int off = 1; off < 64; off <<= 1) {
        s  += __shfl_xor(s,  off);
        s2 += __shfl_xor(s2, off);
    }
    __shared__ float red[8];
    const int wave = tid >> 6, lane = tid & 63;
    if (lane == 0) { red[wave] = s; red[wave + 4] = s2; }
    __syncthreads();
    s  = red[0] + red[1] + red[2] + red[3];
    s2 = red[4] + red[5] + red[6] + red[7];
    const float mu  = s * (1.0f / DIMC);
    const float var = s2 * (1.0f / DIMC) - mu * mu;
    const float inv = rsqrtf(fmaxf(var, 0.f) + 1e-5f);
    for (int i = 0; i < 4; i++) {
        int idx = tid + i * 256;
        float o = (v[i] - mu) * inv * load_elem(g, idx, isbf) + load_elem(b, idx, isbf);
        out[base + idx] = f2bf(o);
    }
}

// ---------------------------------------------------------------------------
// FUSED split-K reduce + LayerNorm. One block per token. Partials are BF16.
// v = p0 + p1 + bias[col] + resid(raw dtype); x1f <- v (fp32, needed later as
// residual); h <- LN(v; g,b) bf16.
// Aliasing: pa lives in vtg region, p1 in its own alloc; x1f (qb+kb) is
// disjoint from both -> no read/write overlap.
// ---------------------------------------------------------------------------
__global__ __launch_bounds__(256) void reduce_ln(
    const ushort_t* __restrict__ p0, const ushort_t* __restrict__ p1,
    const void* __restrict__ bias, const void* __restrict__ resid,
    float* __restrict__ x1f, const void* __restrict__ g,
    const void* __restrict__ b, const int* __restrict__ flag,
    ushort_t* __restrict__ out)
{
    const int isbf = *flag;
    const int t = blockIdx.x;
    const int tid = threadIdx.x;
    const size_t base = (size_t)t * DIMC;
    const int col = tid * 4;
    const size_t i = base + col;
    const uint2 au = *(const uint2*)&p0[i];
    const uint2 bu = *(const uint2*)&p1[i];
    float v[4];
    v[0] = bf2f((ushort_t)(au.x & 0xffff)) + bf2f((ushort_t)(bu.x & 0xffff));
    v[1] = bf2f((ushort_t)(au.x >> 16))    + bf2f((ushort_t)(bu.x >> 16));
    v[2] = bf2f((ushort_t)(au.y & 0xffff)) + bf2f((ushort_t)(bu.y & 0xffff));
    v[3] = bf2f((ushort_t)(au.y >> 16))    + bf2f((ushort_t)(bu.y >> 16));
    for (int c = 0; c < 4; c++) {
        v[c] += load_elem(bias, col + c, isbf);
        v[c] += load_elem(resid, i + c, isbf);
    }
    *(float4*)&x1f[i] = make_float4(v[0], v[1], v[2], v[3]);

    float s  = v[0] + v[1] + v[2] + v[3];
    float s2 = v[0]*v[0] + v[1]*v[1] + v[2]*v[2] + v[3]*v[3];
    for (int off = 1; off < 64; off <<= 1) {
        s  += __shfl_xor(s,  off);
        s2 += __shfl_xor(s2, off);
    }
    __shared__ float red[8];
    const int wave = tid >> 6, lane = tid & 63;
    if (lane == 0) { red[wave] = s; red[wave + 4] = s2; }
    __syncthreads();
    s  = red[0] + red[1] + red[2] + red[3];
    s2 = red[4] + red[5] + red[6] + red[7];
    const float mu  = s * (1.0f / DIMC);
    const float var = s2 * (1.0f / DIMC) - mu * mu;
    const float inv = rsqrtf(fmaxf(var, 0.f) + 1e-5f);
    ushort_t ob[4];
    for (int c = 0; c < 4; c++) {
        float o = (v[c] - mu) * inv * load_elem(g, col + c, isbf)
                + load_elem(b, col + c, isbf);
        ob[c] = f2bf(o);
    }
    unsigned int lo = (unsigned int)ob[0] | ((unsigned int)ob[1] << 16);
    unsigned int hi = (unsigned int)ob[2] | ((unsigned int)ob[3] << 16);
    *(uint2*)&out[i] = make_uint2(lo, hi);
}

// ---------------------------------------------------------------------------
// GEMM: C[M,N] = A[M,K] @ BT[N,K]^T + bias (+resid) (+gelu)
// BM=128, BN in {128,64}, BK=32, 4 waves. global_load_lds width-16 staging.
// NBUF=3: triple-buffered + counted vmcnt(SPW) + raw s_barrier (stage(t+1)
//         stays in flight across the barrier; lgkmcnt(0) seals WAR) +
//         T5 s_setprio(1) around the MFMA cluster (measured null, harmless).
// T1 XCD swizzle: orig=by*gx+bx; swz=(orig%8)*(nwg/8)+orig/8 -> each XCD
// owns a contiguous logical-tile chunk. Bijective (nwg%8==0 everywhere).
// LDS slot swizzle sigma(s)=s^((s>>3)&7) per 1KB segment, both sides.
// Verified R14: bank conflicts 6.29M -> 0.
// BN=128 requires >=3 blocks/CU to pay (FF1 1024-block / QKV 768-block
// grids); 512-block split-K grids stay BN=64 (R18: FF2@BN128 2/CU 63->84us).
// RES: 0 none, 1 raw resid (dtype per flag), 2 f32 resid (ws).
// ACT: 0 none, 1 gelu.
// OUTF: 0 bf16 out0, 1 f32 out0, 2 flag-dep out0,
//       3 QKV split-1024 (Q->out0, K->out1, V->out2 TRANSPOSED [b*1024+n][s]),
//       4 split-K BF16 partial: blockIdx.z selects K-chunk; output pointer
//         z==0->out0, 1->out1, 2->out2, 3->resid (slot reused; RES==0 here).
// ---------------------------------------------------------------------------
template<int BN, int RES, int ACT, int OUTF, int NBUF>
__global__ __launch_bounds__(256) void gemm_bt(
    const ushort_t* __restrict__ A, const ushort_t* __restrict__ BT,
    const void* __restrict__ bias0, const void* __restrict__ bias1,
    const void* __restrict__ bias2, const void* __restrict__ resid,
    void* __restrict__ out0, void* __restrict__ out1, void* __restrict__ out2,
    int M, int N, int K, int Ksub, const int* __restrict__ flag)
{
    constexpr int BM   = 128;
    constexpr int JF   = BN / 32;        // j-fragments per wave
    constexpr int ASEG = BM / 16;        // 1KB segments in As
    constexpr int SPW  = (BM + BN) / 64; // segments per wave (stage loads/wave)
    __shared__ __align__(16) ushort_t As[NBUF][BM][32];
    __shared__ __align__(16) ushort_t Bs[NBUF][BN][32];
    const int isbf = *flag;
    const int tid = threadIdx.x, lane = tid & 63, wave = tid >> 6;

    // ---- T1: XCD-aware bijective block swizzle (x fastest in dispatch) ----
    int bx, by;
    {
        const int gx = gridDim.x, gy = gridDim.y;
        const int nwg = gx * gy;              // % 8 == 0 at all call sites
        const int orig = blockIdx.y * gx + blockIdx.x;
        const int cpx = nwg >> 3;
        const int swz = (orig & 7) * cpx + (orig >> 3);
        bx = swz % gx;
        by = swz / gx;
    }
    const int m0 = by * BM, n0 = bx * BN;
    const int wm = (wave & 1) * 64;
    const int wn = (wave >> 1) * (BN / 2);
    const int lm = lane & 15, quad = lane >> 4;

    const void* biasp = bias0;
    void* outp = out0;
    int nout = N;
    int colmask = 0x7fffffff;
    int sel = 0;
    if (OUTF == 3) {
        sel = n0 >> 10;                         // block-uniform (1024%BN==0)
        biasp = sel == 0 ? bias0 : (sel == 1 ? bias1 : bias2);
        outp  = sel == 0 ? out0  : (sel == 1 ? out1  : out2);
        nout = 1024; colmask = 1023;
    }
    int kbeg = 0;
    if (OUTF == 4) {
        const int z = blockIdx.z;
        kbeg = z * Ksub;
        outp = z == 0 ? out0 : (z == 1 ? out1 : (z == 2 ? out2 : (void*)resid));
    }

    f32x4 acc[4][JF];
    for (int i = 0; i < 4; i++)
        for (int j = 0; j < JF; j++)
            acc[i][j] = (f32x4){0.f, 0.f, 0.f, 0.f};

    // ---- slot swizzle: sigma(s) = s ^ ((s>>3)&7), involution on 0..63 ----
    const int lsw  = lane ^ ((lane >> 3) & 7);
    const int lrow = lsw >> 2;           // swizzled row within 16-row segment
    const int lcol = (lsw & 3) * 8;      // swizzled 8-ushort chunk offset
    const int srd  = (4 * lm + quad);
    const int srz  = srd ^ ((srd >> 3) & 7);
    const int rsw  = srz >> 2;           // physical row-in-segment to read
    const int csw  = (srz & 3) * 8;      // physical ushort col to read

    // Per-wave staging pointers. seg (wave-uniform) picks A vs B panel;
    // global pointer advances by 32 elems (64 B) per K-step.
    const ushort_t* gpp[SPW];
    ushort_t* lpp[NBUF][SPW];
#pragma unroll
    for (int s = 0; s < SPW; s++) {
        const int seg = wave * SPW + s;
        if (seg < ASEG) {
            gpp[s] = &A[(size_t)(m0 + seg * 16 + lrow) * K + kbeg + lcol];
#pragma unroll
            for (int bfi = 0; bfi < NBUF; bfi++) lpp[bfi][s] = &As[bfi][seg * 16][0];
        } else {
            gpp[s] = &BT[(size_t)(n0 + (seg - ASEG) * 16 + lrow) * K + kbeg + lcol];
#pragma unroll
            for (int bfi = 0; bfi < NBUF; bfi++) lpp[bfi][s] = &Bs[bfi][(seg - ASEG) * 16][0];
        }
    }

#define GEMM_STAGE(BUF, T)                                                    \
    {                                                                         \
        _Pragma("unroll")                                                     \
        for (int s = 0; s < SPW; s++)                                         \
            __builtin_amdgcn_global_load_lds(                                 \
                (const __attribute__((address_space(1))) unsigned int*)       \
                    (gpp[s] + (size_t)(T) * 32),                              \
                (__attribute__((address_space(3))) unsigned int*)lpp[BUF][s], \
                16, 0, 0);                                                    \
    }

#define GEMM_COMPUTE(BUF)                                                     \
    {                                                                         \
        short8 af[4], bfr[JF];                                                \
        _Pragma("unroll")                                                     \
        for (int i = 0; i < 4; i++)                                           \
            af[i] = *(const short8*)&As[BUF][wm + i * 16 + rsw][csw];         \
        _Pragma("unroll")                                                     \
        for (int j = 0; j < JF; j++)                                          \
            bfr[j] = *(const short8*)&Bs[BUF][wn + j * 16 + rsw][csw];        \
        _Pragma("unroll")                                                     \
        for (int i = 0; i < 4; i++)                                           \
            _Pragma("unroll")                                                 \
            for (int j = 0; j < JF; j++)                                      \
                acc[i][j] = __builtin_amdgcn_mfma_f32_16x16x32_bf16(          \
                    af[i], bfr[j], acc[i][j], 0, 0, 0);                       \
    }

    // NBUF=3 step: pre-barrier wait vmcnt(SPW) => stage(T) landed while
    // stage(T+1)'s SPW loads stay in flight; lgkmcnt(0) => this wave's
    // ds_reads of buffer BS (overwritten after the barrier) are in regs.
#define GEMM_STEP(BC, BS, T)                                                  \
    if ((T) < nt) {                                                           \
        if ((T) + 1 < nt) {                                                   \
            if constexpr (SPW == 3)                                           \
                asm volatile("s_waitcnt vmcnt(3) lgkmcnt(0)" ::: "memory");   \
            else                                                              \
                asm volatile("s_waitcnt vmcnt(4) lgkmcnt(0)" ::: "memory");   \
        } else {                                                              \
            asm volatile("s_waitcnt vmcnt(0) lgkmcnt(0)" ::: "memory");       \
        }                                                                     \
        __builtin_amdgcn_s_barrier();                                         \
        __builtin_amdgcn_sched_barrier(0);                                    \
        if ((T) + 2 < nt) GEMM_STAGE(BS, (T) + 2);                            \
        __builtin_amdgcn_s_setprio(1);                                        \
        GEMM_COMPUTE(BC);                                                     \
        __builtin_amdgcn_s_setprio(0);                                        \
    }

    const int nt = Ksub / 32;   // in {16, 32, 64}; guards handle any nt
    if constexpr (NBUF == 3) {
        GEMM_STAGE(0, 0);
        GEMM_STAGE(1, 1);
        for (int t = 0; t < nt; t += 3) {
            GEMM_STEP(0, 2, t);
            GEMM_STEP(1, 0, t + 1);
            GEMM_STEP(2, 1, t + 2);
        }
    } else {
        GEMM_STAGE(0, 0);
        __syncthreads();
        for (int t = 0; t < nt; t += 2) {
            GEMM_STAGE(1, t + 1);
            GEMM_COMPUTE(0);
            __syncthreads();
            if (t + 2 < nt) GEMM_STAGE(0, t + 2);
            GEMM_COMPUTE(1);
            __syncthreads();
        }
    }
#undef GEMM_STEP
#undef GEMM_STAGE
#undef GEMM_COMPUTE

    if (OUTF == 3 && sel == 2) {
        // V output, transposed: vtg[(b*1024 + col)][s], s = token % 2048.
        for (int j = 0; j < JF; j++) {
            const int colo = (n0 + wn + j * 16 + lm) & 1023;
            const float bv = load_elem(biasp, colo, isbf);
            for (int i = 0; i < 4; i++) {
                const int token = m0 + wm + i * 16 + quad * 4;
                const int bb = token >> 11, ss = token & 2047;
                unsigned int lo = (unsigned int)f2bf(acc[i][j][0] + bv)
                                | ((unsigned int)f2bf(acc[i][j][1] + bv) << 16);
                unsigned int hi = (unsigned int)f2bf(acc[i][j][2] + bv)
                                | ((unsigned int)f2bf(acc[i][j][3] + bv) << 16);
                *(uint2*)&((ushort_t*)outp)[(size_t)((bb << 10) + colo) * SEQ + ss] =
                    make_uint2(lo, hi);
            }
        }
        return;
    }

    for (int j = 0; j < JF; j++) {
        const int col  = n0 + wn + j * 16 + lm;
        const int colo = col & colmask;
        const float bv = (OUTF == 4) ? 0.f : load_elem(biasp, colo, isbf);
        for (int i = 0; i < 4; i++) {
            const int rbase = m0 + wm + i * 16 + quad * 4;
            for (int r = 0; r < 4; r++) {
                const size_t oi = (size_t)(rbase + r) * nout + colo;
                float v2 = acc[i][j][r] + bv;
                if (ACT == 1) v2 = gelu_f(v2);
                if (RES == 1) v2 += load_elem(resid, oi, isbf);
                if (RES == 2) v2 += ((const float*)resid)[oi];
                if (OUTF == 1)      { ((float*)outp)[oi] = v2; }
                else if (OUTF == 4) { ((ushort_t*)outp)[oi] = f2bf(v2); }
                else if (OUTF == 2) {
                    if (isbf) ((ushort_t*)outp)[oi] = f2bf(v2);
                    else      ((float*)outp)[oi] = v2;
                }
                else                { ((ushort_t*)outp)[oi] = f2bf(v2); }
            }
        }
    }
}

// ---------------------------------------------------------------------------
// Split-K reduce (2 BF16 partials): out = p0 + p1 + bias[col] + resid(f32 ws),
// flag-dtype out. Disjoint regions (p0=ao, p1 own alloc, resid=x1f, out=d_out).
// ---------------------------------------------------------------------------
__global__ __launch_bounds__(256) void splitk_reduce(
    const ushort_t* __restrict__ p0, const ushort_t* __restrict__ p1,
    const void* __restrict__ bias, const float* __restrict__ resid,
    void* __restrict__ out, const int* __restrict__ flag)
{
    const int isbf = *flag;
    const size_t i = ((size_t)blockIdx.x * 256 + threadIdx.x) * 4;
    const uint2 au = *(const uint2*)&p0[i];
    const uint2 bu = *(const uint2*)&p1[i];
    const float4 r = *(const float4*)&resid[i];
    const int col = (int)(i & 1023);
    float v[4];
    v[0] = bf2f((ushort_t)(au.x & 0xffff)) + bf2f((ushort_t)(bu.x & 0xffff)) + r.x;
    v[1] = bf2f((ushort_t)(au.x >> 16))    + bf2f((ushort_t)(bu.x >> 16))    + r.y;
    v[2] = bf2f((ushort_t)(au.y & 0xffff)) + bf2f((ushort_t)(bu.y & 0xffff)) + r.z;
    v[3] = bf2f((ushort_t)(au.y >> 16))    + bf2f((ushort_t)(bu.y >> 16))    + r.w;
    for (int c = 0; c < 4; c++) v[c] += load_elem(bias, col + c, isbf);
    if (isbf) {
        unsigned int lo = (unsigned int)f2bf(v[0]) | ((unsigned int)f2bf(v[1]) << 16);
        unsigned int hi = (unsigned int)f2bf(v[2]) | ((unsigned int)f2bf(v[3]) << 16);
        *(uint2*)&((ushort_t*)out)[i] = make_uint2(lo, hi);
    } else {
        *(float4*)&((float*)out)[i] = make_float4(v[0], v[1], v[2], v[3]);
    }
}

// ---------------------------------------------------------------------------
// MFMA flash attention, S^T orientation, base-2 softmax, no max-subtraction.
// Q-tile 128, register double-buffered K/V staging.
// LDS: Ps aliases Qs[128][72] (both 18432B). Ks/Vt in GEMM-geometry
// segments: [2 col-halves][64 rows][32 ushorts], slot sigma swizzle both
// sides (R14-verified 0-conflict read pattern). Total LDS 34.8KB.
// ---------------------------------------------------------------------------
__global__ __launch_bounds__(256) void attn_kernel(
    const ushort_t* __restrict__ q, const ushort_t* __restrict__ k,
    const ushort_t* __restrict__ vt, ushort_t* __restrict__ o)
{
    const int bh = blockIdx.x;
    const int b  = bh >> 4, h = bh & 15;
    const int q0 = blockIdx.y * 128;
    const int tid = threadIdx.x, lane = tid & 63, wave = tid >> 6;
    const int lm = lane & 15, quad = lane >> 4;

    __shared__ ushort_t Qs[128][72];     // reused as Ps[4][32][72] in the loop
    __shared__ __align__(16) ushort_t Ks2[2][64][32];
    __shared__ __align__(16) ushort_t Vt2[2][64][32];
    typedef ushort_t PsRow[32][72];
    PsRow* Ps = reinterpret_cast<PsRow*>(&Qs[0][0]);   // Ps[wave][row][col]

    const size_t base  = ((size_t)b * SEQ) * DIMC + h * 64;
    const size_t vbase = ((size_t)b * DIMC + h * 64) * SEQ;

    {
        const int er0 = (tid * 8) >> 6;
        const int ec0 = (tid * 8) & 63;
        for (int half = 0; half < 4; half++) {
            const int r = er0 + half * 32;
            short8 qq = *(const short8*)&q[base + (size_t)(q0 + r) * DIMC + ec0];
            short8 qs;
            for (int i = 0; i < 8; i++)
                qs[i] = (short)f2bf(bf2f((ushort_t)qq[i]) * 0.18033688011112042f);
            *(short8*)&Qs[r][ec0] = qs;
        }
    }
    __syncthreads();

    short8 qf[2][2];
    for (int qh = 0; qh < 2; qh++)
        for (int ks = 0; ks < 2; ks++)
            qf[qh][ks] = *(const short8*)&Qs[wave * 32 + qh * 16 + lm][quad * 8 + ks * 32];

    short8 onef;
    for (int i = 0; i < 8; i++) onef[i] = (short)0x3F80;

    f32x4 oacc[4][2], lacc[2];
    for (int j = 0; j < 4; j++)
        for (int qh = 0; qh < 2; qh++) oacc[j][qh] = (f32x4){0.f, 0.f, 0.f, 0.f};
    lacc[0] = (f32x4){0.f, 0.f, 0.f, 0.f};
    lacc[1] = (f32x4){0.f, 0.f, 0.f, 0.f};

    // ---- K/V staging coords + swizzled write slots ----
    const int er = (tid * 8) >> 6;       // 0..31 (row; +32 for kreg1)
    const int ec = (tid * 8) & 63;       // 8-aligned col
    const int half_k = ec >> 5;          // col half
    const int chk_k  = (ec & 31) >> 3;   // 16B chunk within half (0..3)
    const int ks_s   = 4 * (er & 15) + chk_k;
    const int ks_z   = ks_s ^ ((ks_s >> 3) & 7);
    const int kw_r   = (er & ~15) + (ks_z >> 2);   // rows er / er+32 share sigma
    const int kw_c   = (ks_z & 3) * 8;

    const int dd = tid >> 2;             // 0..63 (V row)
    const int kg = tid & 3;
    const int half_v = kg >> 1;
    const int chv0 = 2 * (kg & 1);
    const int vs0 = 4 * (dd & 15) + chv0,     vz0 = vs0 ^ ((vs0 >> 3) & 7);
    const int vs1 = 4 * (dd & 15) + chv0 + 1, vz1 = vs1 ^ ((vs1 >> 3) & 7);
    const int vw_r0 = (dd & ~15) + (vz0 >> 2), vw_c0 = (vz0 & 3) * 8;
    const int vw_r1 = (dd & ~15) + (vz1 >> 2), vw_c1 = (vz1 & 3) * 8;

    // read side: logical (row lm in segment, chunk quad) -> sigma slot
    const int srd = 4 * lm + quad;
    const int srz = srd ^ ((srd >> 3) & 7);
    const int rsw = srz >> 2, csw = (srz & 3) * 8;

    short8 kreg0, kreg1, vreg0, vreg1;
    {
        kreg0 = *(const short8*)&k[base + (size_t)(er) * DIMC + ec];
        kreg1 = *(const short8*)&k[base + (size_t)(er + 32) * DIMC + ec];
        const size_t vsrc = vbase + (size_t)dd * SEQ + kg * 16;
        vreg0 = *(const short8*)&vt[vsrc];
        vreg1 = *(const short8*)&vt[vsrc + 8];
    }

    for (int kt = 0; kt < SEQ / 64; kt++) {
        __syncthreads();   // drains each wave's own ds_reads (qf / prior tiles)
        *(short8*)&Ks2[half_k][kw_r][kw_c]      = kreg0;
        *(short8*)&Ks2[half_k][kw_r + 32][kw_c] = kreg1;
        *(short8*)&Vt2[half_v][vw_r0][vw_c0]    = vreg0;
        *(short8*)&Vt2[half_v][vw_r1][vw_c1]    = vreg1;
        __syncthreads();
        if (kt + 1 < SEQ / 64) {
            const int kn = (kt + 1) * 64;
            kreg0 = *(const short8*)&k[base + (size_t)(kn + er) * DIMC + ec];
            kreg1 = *(const short8*)&k[base + (size_t)(kn + er + 32) * DIMC + ec];
            const size_t vsrc = vbase + (size_t)dd * SEQ + kn + kg * 16;
            vreg0 = *(const short8*)&vt[vsrc];
            vreg1 = *(const short8*)&vt[vsrc + 8];
        }

        f32x4 st[4][2];
        for (int j = 0; j < 4; j++)
            for (int qh = 0; qh < 2; qh++) st[j][qh] = (f32x4){0.f, 0.f, 0.f, 0.f};
        for (int ks = 0; ks < 2; ks++) {
            for (int j = 0; j < 4; j++) {
                short8 kf = *(const short8*)&Ks2[ks][j * 16 + rsw][csw];
                for (int qh = 0; qh < 2; qh++)
                    st[j][qh] = __builtin_amdgcn_mfma_f32_16x16x32_bf16(kf, qf[qh][ks], st[j][qh], 0, 0, 0);
            }
        }

        for (int j = 0; j < 4; j++)
            for (int qh = 0; qh < 2; qh++) {
                unsigned int u0 = __float_as_uint(__builtin_amdgcn_exp2f(st[j][qh][0]));
                unsigned int u1 = __float_as_uint(__builtin_amdgcn_exp2f(st[j][qh][1]));
                unsigned int u2 = __float_as_uint(__builtin_amdgcn_exp2f(st[j][qh][2]));
                unsigned int u3 = __float_as_uint(__builtin_amdgcn_exp2f(st[j][qh][3]));
                unsigned int lo = (u1 & 0xffff0000u) | (u0 >> 16);
                unsigned int hi = (u3 & 0xffff0000u) | (u2 >> 16);
                *(uint2*)&Ps[wave][qh * 16 + lm][j * 16 + quad * 4] = make_uint2(lo, hi);
            }

        for (int ks = 0; ks < 2; ks++) {
            for (int qh = 0; qh < 2; qh++) {
                short8 pf = *(const short8*)&Ps[wave][qh * 16 + lm][quad * 8 + ks * 32];
                lacc[qh] = __builtin_amdgcn_mfma_f32_16x16x32_bf16(pf, onef, lacc[qh], 0, 0, 0);
                for (int j = 0; j < 4; j++) {
                    short8 vf = *(const short8*)&Vt2[ks][j * 16 + rsw][csw];
                    oacc[j][qh] = __builtin_amdgcn_mfma_f32_16x16x32_bf16(pf, vf, oacc[j][qh], 0, 0, 0);
                }
            }
        }
    }

    float rinv[2][4];
    for (int qh = 0; qh < 2; qh++)
        for (int r = 0; r < 4; r++) rinv[qh][r] = 1.0f / fmaxf(lacc[qh][r], 1e-30f);

    for (int j = 0; j < 4; j++)
        for (int qh = 0; qh < 2; qh++)
            for (int r = 0; r < 4; r++) {
                const int row = q0 + wave * 32 + qh * 16 + quad * 4 + r;
                o[base + (size_t)row * DIMC + j * 16 + lm] = f2bf(oacc[j][qh][r] * rinv[qh][r]);
            }
}

// ---------------------------------------------------------------------------
extern "C" void kernel_launch(void* const* d_in, const int* in_sizes, int n_in,
                              void* d_out, int out_size, void* d_ws, size_t ws_size,
                              hipStream_t stream)
{
    const void* x   = d_in[0];
    const void* g1  = d_in[1];
    const void* b1  = d_in[2];
    const void* Wq  = d_in[3];
    const void* bq  = d_in[4];
    const void* Wk  = d_in[5];
    const void* bk  = d_in[6];
    const void* Wv  = d_in[7];
    const void* bv  = d_in[8];
    const void* Wo  = d_in[9];
    const void* bo  = d_in[10];
    const void* g2  = d_in[11];
    const void* b2  = d_in[12];
    const void* W1  = d_in[13];
    const void* bf1 = d_in[14];
    const void* W2  = d_in[15];
    const void* bf2 = d_in[16];

    const size_t SZ_TOKD_BF = (size_t)TOKENS * DIMC * 2;      //  8 MB
    const size_t SZ_TOKD_F  = (size_t)TOKENS * DIMC * 4;      // 16 MB
    const size_t SZ_W_SQ    = (size_t)DIMC * DIMC * 2;        //  2 MB
    const size_t SZ_W_FF    = (size_t)DIMC * HID * 2;         //  8 MB
    const size_t SZ_FF1     = (size_t)TOKENS * HID * 2;       // 32 MB

    char* ws = (char*)d_ws;
    size_t off = 0;
    int*      flag = (int*)(ws + off);       off += 256;
    ushort_t* h    = (ushort_t*)(ws + off);  off += SZ_TOKD_BF;
    ushort_t* qb   = (ushort_t*)(ws + off);  off += SZ_TOKD_BF;
    ushort_t* kb_  = (ushort_t*)(ws + off);  off += SZ_TOKD_BF;
    ushort_t* ao   = (ushort_t*)(ws + off);  off += SZ_TOKD_BF;  // attn out
    ushort_t* vtg  = (ushort_t*)(ws + off);  off += SZ_TOKD_BF;  // V transposed
    float*    x1f  = (float*)qb;             // 16MB over qb+kb (dead after attn)
    ushort_t* pa   = (ushort_t*)vtg;         // O-proj bf16 partial 0 (vtg dead after attn)
    ushort_t* p0   = (ushort_t*)ao;          // FF2 bf16 partial 0 (ao dead after O-proj)
    ushort_t* wqt  = (ushort_t*)(ws + off);  off += SZ_W_SQ;   // wq/wk/wv/wo CONTIGUOUS
    ushort_t* wkt  = (ushort_t*)(ws + off);  off += SZ_W_SQ;
    ushort_t* wvt  = (ushort_t*)(ws + off);  off += SZ_W_SQ;
    ushort_t* wot  = (ushort_t*)(ws + off);  off += SZ_W_SQ;
    ushort_t* w1t  = (ushort_t*)(ws + off);  off += SZ_W_FF;
    ushort_t* w2t  = (ushort_t*)(ws + off);  off += SZ_W_FF;
    ushort_t* ff1  = (ushort_t*)(ws + off);  off += SZ_FF1;
    ushort_t* p1   = (ushort_t*)(ws + off);  off += SZ_TOKD_F; // bf16 partial 1 (8MB used)
    if (ws_size < off) return;   // insufficient workspace (output stays 0: diagnostic)

    (void)wkt; (void)wvt;

    detect_dtype<<<1, 256, 0, stream>>>((const ushort_t*)x, flag);

    // all weight transposes (+conversion) in one flat dispatch
    transpose_w_all<<<12288, 256, 0, stream>>>(Wq, Wk, Wv, Wo, W1, W2,
                                               wqt, w1t, w2t, flag);

    // LN1 (x raw, dtype per flag)
    ln_kernel<0><<<TOKENS, 256, 0, stream>>>(x, g1, b1, flag, h);

    // fused QKV projection: N=3072, BN=128, NBUF=3 (48KB -> 3/CU; 768 blocks
    // = EXACTLY one pass); V -> vtg transposed
    gemm_bt<128, 0, 0, 3, 3><<<dim3(24, 32), 256, 0, stream>>>(
        h, wqt, bq, bk, bv, nullptr, qb, kb_, vtg, TOKENS, 3072, DIMC, DIMC, flag);

    // attention -> ao (Q-tile 128; conflict-free K/V LDS)
    attn_kernel<<<dim3(32, 16), 256, 0, stream>>>(qb, kb_, vtg, ao);

    // O projection split-K=2, BN=64 -> bf16 partials pa(vtg) / p1
    gemm_bt<64, 0, 0, 4, 3><<<dim3(16, 32, 2), 256, 0, stream>>>(
        ao, wot, nullptr, nullptr, nullptr, nullptr, pa, p1, nullptr,
        TOKENS, DIMC, DIMC, DIMC / 2, flag);

    // FUSED: x1f = pa + p1 + bo + x (raw resid); h = LN(x1f; g2,b2)
    reduce_ln<<<TOKENS, 256, 0, stream>>>(
        pa, p1, bo, x, x1f, g2, b2, flag, h);

    // FF1 + GELU, BN=128 (1024 blocks; 48KB LDS -> 3/CU; 16 MFMA/step/wave)
    gemm_bt<128, 0, 1, 0, 3><<<dim3(32, 32), 256, 0, stream>>>(
        h, w1t, bf1, nullptr, nullptr, nullptr, ff1, nullptr, nullptr,
        TOKENS, HID, DIMC, DIMC, flag);

    // FF2 split-K=2, BN=64 -> bf16 partials p0(ao) / p1
    gemm_bt<64, 0, 0, 4, 3><<<dim3(16, 32, 2), 256, 0, stream>>>(
        ff1, w2t, nullptr, nullptr, nullptr, nullptr, p0, p1, nullptr,
        TOKENS, DIMC, HID, HID / 2, flag);

    // reduce: d_out = cast(p0 + p1 + bf2 + x1f), dtype per flag
    splitk_reduce<<<TOKENS * DIMC / 1024, 256, 0, stream>>>(
        p0, p1, bf2, x1f, d_out, flag);
}

// Round 16
// 380.400 us; speedup vs baseline: 1.0510x; 1.0510x over previous
//
#include <hip/hip_runtime.h>
#include <hip/hip_bf16.h>
#include <math.h>

// ---------------------------------------------------------------------------
// TransformerBlock on MI355X (gfx950).
// B=2, N=2048 (M=4096 tokens), DIM=1024, HEADS=16, HEAD_DIM=64, HIDDEN=4096.
// R24->R25: FF2 -> BN=128 + split-K=4 (grid (8,32,4) = 1024 blocks, 48KB LDS
// = 3 blocks/CU). R18 showed BN=128 fails at 2/CU (512 blocks); R21 showed
// split-4 fails at BN=64 (no density gain). This pairs 16-MFMA steps WITH
// >=3 blocks/CU — the proven FF1 regime. bf16 partials (R24, absmax-neutral):
// p0=ao, p1 own, p2=vtg (pa dead after reduce_ln), p3=wqt..wot (dead after
// FF1). New bf16 splitk4_reduce. O-proj stays BN=64/split-2 (nt=8 too short).
// ---------------------------------------------------------------------------

typedef unsigned short ushort_t;
typedef short short8 __attribute__((ext_vector_type(8)));
typedef float f32x4 __attribute__((ext_vector_type(4)));

#define TOKENS 4096
#define SEQ    2048
#define DIMC   1024
#define HID    4096

__device__ __forceinline__ float bf2f(ushort_t u) {
    union { float f; unsigned int u; } c; c.u = ((unsigned int)u) << 16; return c.f;
}
__device__ __forceinline__ ushort_t f2bf(float f) {
    union { float f; unsigned int u; } c; c.f = f;
    unsigned int u = c.u;
    unsigned int r = u + 0x7fffu + ((u >> 16) & 1u);   // round-nearest-even
    return (ushort_t)(r >> 16);
}
// tanh-approx GELU (max |err| vs exact ~1e-3; cheap: one __expf)
__device__ __forceinline__ float gelu_f(float x) {
    const float y = 0.79788456080286536f * (x + 0.044715f * x * x * x);
    const float t = __expf(-2.0f * fabsf(y));          // in (0,1]
    const float th = (1.0f - t) / (1.0f + t);          // tanh(|y|)
    return 0.5f * x * (1.0f + copysignf(th, y));
}
__device__ __forceinline__ float load_elem(const void* p, size_t i, int isbf) {
    return isbf ? bf2f(((const ushort_t*)p)[i]) : ((const float*)p)[i];
}

// ---------------------------------------------------------------------------
// Detect input dtype. flag[0] = 1 (bf16) / 0 (fp32); flag[1] = constant 1.
// ---------------------------------------------------------------------------
__global__ __launch_bounds__(256) void detect_dtype(
    const ushort_t* __restrict__ x, int* __restrict__ flag)
{
    __shared__ int bad;
    if (threadIdx.x == 0) bad = 0;
    __syncthreads();
    for (int i = threadIdx.x; i < 4096; i += 256) {
        float v = bf2f(x[i]);
        if (!(fabsf(v) <= 1e6f)) bad = 1;   // catches huge AND NaN
    }
    __syncthreads();
    if (threadIdx.x == 0) { flag[0] = (bad == 0) ? 1 : 0; flag[1] = 1; }
}

// ---------------------------------------------------------------------------
// All 6 weight transposes in ONE flat-grid dispatch.
// tiles: ids 0..4095 -> Wq/Wk/Wv/Wo (1024 tiles each, 32x32 grid),
//        4096..8191 -> W1 (1024x4096: 128x32), 8192..12287 -> W2 (4096x1024: 32x128).
// ---------------------------------------------------------------------------
__global__ __launch_bounds__(256) void transpose_w_all(
    const void* __restrict__ Wq, const void* __restrict__ Wk,
    const void* __restrict__ Wv, const void* __restrict__ Wo,
    const void* __restrict__ W1, const void* __restrict__ W2,
    ushort_t* __restrict__ wsq, ushort_t* __restrict__ w1t,
    ushort_t* __restrict__ w2t, const int* __restrict__ flag)
{
    __shared__ ushort_t tile[32][33];
    const int isbf = *flag;
    const int id = blockIdx.x;
    const void* in; ushort_t* out; int K, N, bx, by;
    if (id < 4096) {
        const int z = id >> 10, t = id & 1023;
        in = z == 0 ? Wq : (z == 1 ? Wk : (z == 2 ? Wv : Wo));
        out = wsq + (size_t)z * DIMC * DIMC;
        K = DIMC; N = DIMC; bx = t & 31; by = t >> 5;
    } else if (id < 8192) {
        const int t = id - 4096;
        in = W1; out = w1t; K = DIMC; N = HID;
        bx = t & 127; by = t >> 7;
    } else {
        const int t = id - 8192;
        in = W2; out = w2t; K = HID; N = DIMC;
        bx = t & 31; by = t >> 5;
    }
    const int kb = by * 32, nb = bx * 32;
    const int tx = threadIdx.x & 31, ty = threadIdx.x >> 5;
    for (int i = 0; i < 4; i++) {
        int k = kb + ty + i * 8;
        tile[ty + i * 8][tx] = f2bf(load_elem(in, (size_t)k * N + nb + tx, isbf));
    }
    __syncthreads();
    for (int i = 0; i < 4; i++) {
        int n = nb + ty + i * 8;
        out[(size_t)n * K + kb + tx] = tile[tx][ty + i * 8];
    }
}

// ---------------------------------------------------------------------------
// LayerNorm over last dim (1024). One block per token, 256 threads.
// INMODE 0: input dtype per flag (raw x). INMODE 1: input always fp32 (ws).
// ---------------------------------------------------------------------------
template<int INMODE>
__global__ __launch_bounds__(256) void ln_kernel(
    const void* __restrict__ in, const void* __restrict__ g,
    const void* __restrict__ b, const int* __restrict__ flag,
    ushort_t* __restrict__ out)
{
    const int isbf = *flag;
    const int t = blockIdx.x;
    const int tid = threadIdx.x;
    const size_t base = (size_t)t * DIMC;
    float v[4];
    for (int i = 0; i < 4; i++) {
        int idx = tid + i * 256;
        v[i] = (INMODE == 1) ? ((const float*)in)[base + idx]
                             : load_elem(in, base + idx, isbf);
    }
    float s  = v[0] + v[1] + v[2] + v[3];
    float s2 = v[0]*v[0] + v[1]*v[1] + v[2]*v[2] + v[3]*v[3];
    for (int off = 1; off < 64; off <<= 1) {
        s  += __shfl_xor(s,  off);
        s2 += __shfl_xor(s2, off);
    }
    __shared__ float red[8];
    const int wave = tid >> 6, lane = tid & 63;
    if (lane == 0) { red[wave] = s; red[wave + 4] = s2; }
    __syncthreads();
    s  = red[0] + red[1] + red[2] + red[3];
    s2 = red[4] + red[5] + red[6] + red[7];
    const float mu  = s * (1.0f / DIMC);
    const float var = s2 * (1.0f / DIMC) - mu * mu;
    const float inv = rsqrtf(fmaxf(var, 0.f) + 1e-5f);
    for (int i = 0; i < 4; i++) {
        int idx = tid + i * 256;
        float o = (v[i] - mu) * inv * load_elem(g, idx, isbf) + load_elem(b, idx, isbf);
        out[base + idx] = f2bf(o);
    }
}

// ---------------------------------------------------------------------------
// FUSED split-K reduce + LayerNorm. One block per token. Partials are BF16.
// v = p0 + p1 + bias[col] + resid(raw dtype); x1f <- v (fp32, needed later as
// residual); h <- LN(v; g,b) bf16.
// Aliasing: pa lives in vtg region, p1 in its own alloc; x1f (qb+kb) is
// disjoint from both -> no read/write overlap.
// ---------------------------------------------------------------------------
__global__ __launch_bounds__(256) void reduce_ln(
    const ushort_t* __restrict__ p0, const ushort_t* __restrict__ p1,
    const void* __restrict__ bias, const void* __restrict__ resid,
    float* __restrict__ x1f, const void* __restrict__ g,
    const void* __restrict__ b, const int* __restrict__ flag,
    ushort_t* __restrict__ out)
{
    const int isbf = *flag;
    const int t = blockIdx.x;
    const int tid = threadIdx.x;
    const size_t base = (size_t)t * DIMC;
    const int col = tid * 4;
    const size_t i = base + col;
    const uint2 au = *(const uint2*)&p0[i];
    const uint2 bu = *(const uint2*)&p1[i];
    float v[4];
    v[0] = bf2f((ushort_t)(au.x & 0xffff)) + bf2f((ushort_t)(bu.x & 0xffff));
    v[1] = bf2f((ushort_t)(au.x >> 16))    + bf2f((ushort_t)(bu.x >> 16));
    v[2] = bf2f((ushort_t)(au.y & 0xffff)) + bf2f((ushort_t)(bu.y & 0xffff));
    v[3] = bf2f((ushort_t)(au.y >> 16))    + bf2f((ushort_t)(bu.y >> 16));
    for (int c = 0; c < 4; c++) {
        v[c] += load_elem(bias, col + c, isbf);
        v[c] += load_elem(resid, i + c, isbf);
    }
    *(float4*)&x1f[i] = make_float4(v[0], v[1], v[2], v[3]);

    float s  = v[0] + v[1] + v[2] + v[3];
    float s2 = v[0]*v[0] + v[1]*v[1] + v[2]*v[2] + v[3]*v[3];
    for (int off = 1; off < 64; off <<= 1) {
        s  += __shfl_xor(s,  off);
        s2 += __shfl_xor(s2, off);
    }
    __shared__ float red[8];
    const int wave = tid >> 6, lane = tid & 63;
    if (lane == 0) { red[wave] = s; red[wave + 4] = s2; }
    __syncthreads();
    s  = red[0] + red[1] + red[2] + red[3];
    s2 = red[4] + red[5] + red[6] + red[7];
    const float mu  = s * (1.0f / DIMC);
    const float var = s2 * (1.0f / DIMC) - mu * mu;
    const float inv = rsqrtf(fmaxf(var, 0.f) + 1e-5f);
    ushort_t ob[4];
    for (int c = 0; c < 4; c++) {
        float o = (v[c] - mu) * inv * load_elem(g, col + c, isbf)
                + load_elem(b, col + c, isbf);
        ob[c] = f2bf(o);
    }
    unsigned int lo = (unsigned int)ob[0] | ((unsigned int)ob[1] << 16);
    unsigned int hi = (unsigned int)ob[2] | ((unsigned int)ob[3] << 16);
    *(uint2*)&out[i] = make_uint2(lo, hi);
}

// ---------------------------------------------------------------------------
// GEMM: C[M,N] = A[M,K] @ BT[N,K]^T + bias (+resid) (+gelu)
// BM=128, BN in {128,64}, BK=32, 4 waves. global_load_lds width-16 staging.
// NBUF=3: triple-buffered + counted vmcnt(SPW) + raw s_barrier (stage(t+1)
//         stays in flight across the barrier; lgkmcnt(0) seals WAR) +
//         T5 s_setprio(1) around the MFMA cluster (measured null, harmless).
// T1 XCD swizzle: orig=by*gx+bx; swz=(orig%8)*(nwg/8)+orig/8 -> each XCD
// owns a contiguous logical-tile chunk. Bijective (nwg%8==0 everywhere).
// LDS slot swizzle sigma(s)=s^((s>>3)&7) per 1KB segment, both sides.
// Verified R14: bank conflicts 6.29M -> 0.
// BN=128 requires >=3 blocks/CU to pay: FF1 1024-block, QKV 768-block,
// FF2 split-K=4 1024-block grids qualify; O-proj (512 at sk2) stays BN=64.
// RES: 0 none, 1 raw resid (dtype per flag), 2 f32 resid (ws).
// ACT: 0 none, 1 gelu.
// OUTF: 0 bf16 out0, 1 f32 out0, 2 flag-dep out0,
//       3 QKV split-1024 (Q->out0, K->out1, V->out2 TRANSPOSED [b*1024+n][s]),
//       4 split-K BF16 partial: blockIdx.z selects K-chunk; output pointer
//         z==0->out0, 1->out1, 2->out2, 3->resid (slot reused; RES==0 here).
// ---------------------------------------------------------------------------
template<int BN, int RES, int ACT, int OUTF, int NBUF>
__global__ __launch_bounds__(256) void gemm_bt(
    const ushort_t* __restrict__ A, const ushort_t* __restrict__ BT,
    const void* __restrict__ bias0, const void* __restrict__ bias1,
    const void* __restrict__ bias2, const void* __restrict__ resid,
    void* __restrict__ out0, void* __restrict__ out1, void* __restrict__ out2,
    int M, int N, int K, int Ksub, const int* __restrict__ flag)
{
    constexpr int BM   = 128;
    constexpr int JF   = BN / 32;        // j-fragments per wave
    constexpr int ASEG = BM / 16;        // 1KB segments in As
    constexpr int SPW  = (BM + BN) / 64; // segments per wave (stage loads/wave)
    __shared__ __align__(16) ushort_t As[NBUF][BM][32];
    __shared__ __align__(16) ushort_t Bs[NBUF][BN][32];
    const int isbf = *flag;
    const int tid = threadIdx.x, lane = tid & 63, wave = tid >> 6;

    // ---- T1: XCD-aware bijective block swizzle (x fastest in dispatch) ----
    int bx, by;
    {
        const int gx = gridDim.x, gy = gridDim.y;
        const int nwg = gx * gy;              // % 8 == 0 at all call sites
        const int orig = blockIdx.y * gx + blockIdx.x;
        const int cpx = nwg >> 3;
        const int swz = (orig & 7) * cpx + (orig >> 3);
        bx = swz % gx;
        by = swz / gx;
    }
    const int m0 = by * BM, n0 = bx * BN;
    const int wm = (wave & 1) * 64;
    const int wn = (wave >> 1) * (BN / 2);
    const int lm = lane & 15, quad = lane >> 4;

    const void* biasp = bias0;
    void* outp = out0;
    int nout = N;
    int colmask = 0x7fffffff;
    int sel = 0;
    if (OUTF == 3) {
        sel = n0 >> 10;                         // block-uniform (1024%BN==0)
        biasp = sel == 0 ? bias0 : (sel == 1 ? bias1 : bias2);
        outp  = sel == 0 ? out0  : (sel == 1 ? out1  : out2);
        nout = 1024; colmask = 1023;
    }
    int kbeg = 0;
    if (OUTF == 4) {
        const int z = blockIdx.z;
        kbeg = z * Ksub;
        outp = z == 0 ? out0 : (z == 1 ? out1 : (z == 2 ? out2 : (void*)resid));
    }

    f32x4 acc[4][JF];
    for (int i = 0; i < 4; i++)
        for (int j = 0; j < JF; j++)
            acc[i][j] = (f32x4){0.f, 0.f, 0.f, 0.f};

    // ---- slot swizzle: sigma(s) = s ^ ((s>>3)&7), involution on 0..63 ----
    const int lsw  = lane ^ ((lane >> 3) & 7);
    const int lrow = lsw >> 2;           // swizzled row within 16-row segment
    const int lcol = (lsw & 3) * 8;      // swizzled 8-ushort chunk offset
    const int srd  = (4 * lm + quad);
    const int srz  = srd ^ ((srd >> 3) & 7);
    const int rsw  = srz >> 2;           // physical row-in-segment to read
    const int csw  = (srz & 3) * 8;      // physical ushort col to read

    // Per-wave staging pointers. seg (wave-uniform) picks A vs B panel;
    // global pointer advances by 32 elems (64 B) per K-step.
    const ushort_t* gpp[SPW];
    ushort_t* lpp[NBUF][SPW];
#pragma unroll
    for (int s = 0; s < SPW; s++) {
        const int seg = wave * SPW + s;
        if (seg < ASEG) {
            gpp[s] = &A[(size_t)(m0 + seg * 16 + lrow) * K + kbeg + lcol];
#pragma unroll
            for (int bfi = 0; bfi < NBUF; bfi++) lpp[bfi][s] = &As[bfi][seg * 16][0];
        } else {
            gpp[s] = &BT[(size_t)(n0 + (seg - ASEG) * 16 + lrow) * K + kbeg + lcol];
#pragma unroll
            for (int bfi = 0; bfi < NBUF; bfi++) lpp[bfi][s] = &Bs[bfi][(seg - ASEG) * 16][0];
        }
    }

#define GEMM_STAGE(BUF, T)                                                    \
    {                                                                         \
        _Pragma("unroll")                                                     \
        for (int s = 0; s < SPW; s++)                                         \
            __builtin_amdgcn_global_load_lds(                                 \
                (const __attribute__((address_space(1))) unsigned int*)       \
                    (gpp[s] + (size_t)(T) * 32),                              \
                (__attribute__((address_space(3))) unsigned int*)lpp[BUF][s], \
                16, 0, 0);                                                    \
    }

#define GEMM_COMPUTE(BUF)                                                     \
    {                                                                         \
        short8 af[4], bfr[JF];                                                \
        _Pragma("unroll")                                                     \
        for (int i = 0; i < 4; i++)                                           \
            af[i] = *(const short8*)&As[BUF][wm + i * 16 + rsw][csw];         \
        _Pragma("unroll")                                                     \
        for (int j = 0; j < JF; j++)                                          \
            bfr[j] = *(const short8*)&Bs[BUF][wn + j * 16 + rsw][csw];        \
        _Pragma("unroll")                                                     \
        for (int i = 0; i < 4; i++)                                           \
            _Pragma("unroll")                                                 \
            for (int j = 0; j < JF; j++)                                      \
                acc[i][j] = __builtin_amdgcn_mfma_f32_16x16x32_bf16(          \
                    af[i], bfr[j], acc[i][j], 0, 0, 0);                       \
    }

    // NBUF=3 step: pre-barrier wait vmcnt(SPW) => stage(T) landed while
    // stage(T+1)'s SPW loads stay in flight; lgkmcnt(0) => this wave's
    // ds_reads of buffer BS (overwritten after the barrier) are in regs.
#define GEMM_STEP(BC, BS, T)                                                  \
    if ((T) < nt) {                                                           \
        if ((T) + 1 < nt) {                                                   \
            if constexpr (SPW == 3)                                           \
                asm volatile("s_waitcnt vmcnt(3) lgkmcnt(0)" ::: "memory");   \
            else                                                              \
                asm volatile("s_waitcnt vmcnt(4) lgkmcnt(0)" ::: "memory");   \
        } else {                                                              \
            asm volatile("s_waitcnt vmcnt(0) lgkmcnt(0)" ::: "memory");       \
        }                                                                     \
        __builtin_amdgcn_s_barrier();                                         \
        __builtin_amdgcn_sched_barrier(0);                                    \
        if ((T) + 2 < nt) GEMM_STAGE(BS, (T) + 2);                            \
        __builtin_amdgcn_s_setprio(1);                                        \
        GEMM_COMPUTE(BC);                                                     \
        __builtin_amdgcn_s_setprio(0);                                        \
    }

    const int nt = Ksub / 32;   // in {16, 32, 64}; guards handle any nt
    if constexpr (NBUF == 3) {
        GEMM_STAGE(0, 0);
        GEMM_STAGE(1, 1);
        for (int t = 0; t < nt; t += 3) {
            GEMM_STEP(0, 2, t);
            GEMM_STEP(1, 0, t + 1);
            GEMM_STEP(2, 1, t + 2);
        }
    } else {
        GEMM_STAGE(0, 0);
        __syncthreads();
        for (int t = 0; t < nt; t += 2) {
            GEMM_STAGE(1, t + 1);
            GEMM_COMPUTE(0);
            __syncthreads();
            if (t + 2 < nt) GEMM_STAGE(0, t + 2);
            GEMM_COMPUTE(1);
            __syncthreads();
        }
    }
#undef GEMM_STEP
#undef GEMM_STAGE
#undef GEMM_COMPUTE

    if (OUTF == 3 && sel == 2) {
        // V output, transposed: vtg[(b*1024 + col)][s], s = token % 2048.
        for (int j = 0; j < JF; j++) {
            const int colo = (n0 + wn + j * 16 + lm) & 1023;
            const float bv = load_elem(biasp, colo, isbf);
            for (int i = 0; i < 4; i++) {
                const int token = m0 + wm + i * 16 + quad * 4;
                const int bb = token >> 11, ss = token & 2047;
                unsigned int lo = (unsigned int)f2bf(acc[i][j][0] + bv)
                                | ((unsigned int)f2bf(acc[i][j][1] + bv) << 16);
                unsigned int hi = (unsigned int)f2bf(acc[i][j][2] + bv)
                                | ((unsigned int)f2bf(acc[i][j][3] + bv) << 16);
                *(uint2*)&((ushort_t*)outp)[(size_t)((bb << 10) + colo) * SEQ + ss] =
                    make_uint2(lo, hi);
            }
        }
        return;
    }

    for (int j = 0; j < JF; j++) {
        const int col  = n0 + wn + j * 16 + lm;
        const int colo = col & colmask;
        const float bv = (OUTF == 4) ? 0.f : load_elem(biasp, colo, isbf);
        for (int i = 0; i < 4; i++) {
            const int rbase = m0 + wm + i * 16 + quad * 4;
            for (int r = 0; r < 4; r++) {
                const size_t oi = (size_t)(rbase + r) * nout + colo;
                float v2 = acc[i][j][r] + bv;
                if (ACT == 1) v2 = gelu_f(v2);
                if (RES == 1) v2 += load_elem(resid, oi, isbf);
                if (RES == 2) v2 += ((const float*)resid)[oi];
                if (OUTF == 1)      { ((float*)outp)[oi] = v2; }
                else if (OUTF == 4) { ((ushort_t*)outp)[oi] = f2bf(v2); }
                else if (OUTF == 2) {
                    if (isbf) ((ushort_t*)outp)[oi] = f2bf(v2);
                    else      ((float*)outp)[oi] = v2;
                }
                else                { ((ushort_t*)outp)[oi] = f2bf(v2); }
            }
        }
    }
}

// ---------------------------------------------------------------------------
// Split-K reduce (2 BF16 partials): out = p0 + p1 + bias[col] + resid(f32 ws),
// flag-dtype out.
// ---------------------------------------------------------------------------
__global__ __launch_bounds__(256) void splitk_reduce(
    const ushort_t* __restrict__ p0, const ushort_t* __restrict__ p1,
    const void* __restrict__ bias, const float* __restrict__ resid,
    void* __restrict__ out, const int* __restrict__ flag)
{
    const int isbf = *flag;
    const size_t i = ((size_t)blockIdx.x * 256 + threadIdx.x) * 4;
    const uint2 au = *(const uint2*)&p0[i];
    const uint2 bu = *(const uint2*)&p1[i];
    const float4 r = *(const float4*)&resid[i];
    const int col = (int)(i & 1023);
    float v[4];
    v[0] = bf2f((ushort_t)(au.x & 0xffff)) + bf2f((ushort_t)(bu.x & 0xffff)) + r.x;
    v[1] = bf2f((ushort_t)(au.x >> 16))    + bf2f((ushort_t)(bu.x >> 16))    + r.y;
    v[2] = bf2f((ushort_t)(au.y & 0xffff)) + bf2f((ushort_t)(bu.y & 0xffff)) + r.z;
    v[3] = bf2f((ushort_t)(au.y >> 16))    + bf2f((ushort_t)(bu.y >> 16))    + r.w;
    for (int c = 0; c < 4; c++) v[c] += load_elem(bias, col + c, isbf);
    if (isbf) {
        unsigned int lo = (unsigned int)f2bf(v[0]) | ((unsigned int)f2bf(v[1]) << 16);
        unsigned int hi = (unsigned int)f2bf(v[2]) | ((unsigned int)f2bf(v[3]) << 16);
        *(uint2*)&((ushort_t*)out)[i] = make_uint2(lo, hi);
    } else {
        *(float4*)&((float*)out)[i] = make_float4(v[0], v[1], v[2], v[3]);
    }
}

// ---------------------------------------------------------------------------
// Split-K reduce (4 BF16 partials): out = p0+p1+p2+p3 + bias[col] + resid(f32),
// flag-dtype out.
// ---------------------------------------------------------------------------
__global__ __launch_bounds__(256) void splitk4_reduce(
    const ushort_t* __restrict__ p0, const ushort_t* __restrict__ p1,
    const ushort_t* __restrict__ p2, const ushort_t* __restrict__ p3,
    const void* __restrict__ bias, const float* __restrict__ resid,
    void* __restrict__ out, const int* __restrict__ flag)
{
    const int isbf = *flag;
    const size_t i = ((size_t)blockIdx.x * 256 + threadIdx.x) * 4;
    const uint2 au = *(const uint2*)&p0[i];
    const uint2 bu = *(const uint2*)&p1[i];
    const uint2 cu = *(const uint2*)&p2[i];
    const uint2 du = *(const uint2*)&p3[i];
    const float4 r = *(const float4*)&resid[i];
    const int col = (int)(i & 1023);
    float v[4];
    v[0] = bf2f((ushort_t)(au.x & 0xffff)) + bf2f((ushort_t)(bu.x & 0xffff))
         + bf2f((ushort_t)(cu.x & 0xffff)) + bf2f((ushort_t)(du.x & 0xffff)) + r.x;
    v[1] = bf2f((ushort_t)(au.x >> 16))    + bf2f((ushort_t)(bu.x >> 16))
         + bf2f((ushort_t)(cu.x >> 16))    + bf2f((ushort_t)(du.x >> 16))    + r.y;
    v[2] = bf2f((ushort_t)(au.y & 0xffff)) + bf2f((ushort_t)(bu.y & 0xffff))
         + bf2f((ushort_t)(cu.y & 0xffff)) + bf2f((ushort_t)(du.y & 0xffff)) + r.z;
    v[3] = bf2f((ushort_t)(au.y >> 16))    + bf2f((ushort_t)(bu.y >> 16))
         + bf2f((ushort_t)(cu.y >> 16))    + bf2f((ushort_t)(du.y >> 16))    + r.w;
    for (int c = 0; c < 4; c++) v[c] += load_elem(bias, col + c, isbf);
    if (isbf) {
        unsigned int lo = (unsigned int)f2bf(v[0]) | ((unsigned int)f2bf(v[1]) << 16);
        unsigned int hi = (unsigned int)f2bf(v[2]) | ((unsigned int)f2bf(v[3]) << 16);
        *(uint2*)&((ushort_t*)out)[i] = make_uint2(lo, hi);
    } else {
        *(float4*)&((float*)out)[i] = make_float4(v[0], v[1], v[2], v[3]);
    }
}

// ---------------------------------------------------------------------------
// MFMA flash attention, S^T orientation, base-2 softmax, no max-subtraction.
// Q-tile 128, register double-buffered K/V staging.
// LDS: Ps aliases Qs[128][72] (both 18432B). Ks/Vt in GEMM-geometry
// segments: [2 col-halves][64 rows][32 ushorts], slot sigma swizzle both
// sides (R14-verified 0-conflict read pattern). Total LDS 34.8KB.
// ---------------------------------------------------------------------------
__global__ __launch_bounds__(256) void attn_kernel(
    const ushort_t* __restrict__ q, const ushort_t* __restrict__ k,
    const ushort_t* __restrict__ vt, ushort_t* __restrict__ o)
{
    const int bh = blockIdx.x;
    const int b  = bh >> 4, h = bh & 15;
    const int q0 = blockIdx.y * 128;
    const int tid = threadIdx.x, lane = tid & 63, wave = tid >> 6;
    const int lm = lane & 15, quad = lane >> 4;

    __shared__ ushort_t Qs[128][72];     // reused as Ps[4][32][72] in the loop
    __shared__ __align__(16) ushort_t Ks2[2][64][32];
    __shared__ __align__(16) ushort_t Vt2[2][64][32];
    typedef ushort_t PsRow[32][72];
    PsRow* Ps = reinterpret_cast<PsRow*>(&Qs[0][0]);   // Ps[wave][row][col]

    const size_t base  = ((size_t)b * SEQ) * DIMC + h * 64;
    const size_t vbase = ((size_t)b * DIMC + h * 64) * SEQ;

    {
        const int er0 = (tid * 8) >> 6;
        const int ec0 = (tid * 8) & 63;
        for (int half = 0; half < 4; half++) {
            const int r = er0 + half * 32;
            short8 qq = *(const short8*)&q[base + (size_t)(q0 + r) * DIMC + ec0];
            short8 qs;
            for (int i = 0; i < 8; i++)
                qs[i] = (short)f2bf(bf2f((ushort_t)qq[i]) * 0.18033688011112042f);
            *(short8*)&Qs[r][ec0] = qs;
        }
    }
    __syncthreads();

    short8 qf[2][2];
    for (int qh = 0; qh < 2; qh++)
        for (int ks = 0; ks < 2; ks++)
            qf[qh][ks] = *(const short8*)&Qs[wave * 32 + qh * 16 + lm][quad * 8 + ks * 32];

    short8 onef;
    for (int i = 0; i < 8; i++) onef[i] = (short)0x3F80;

    f32x4 oacc[4][2], lacc[2];
    for (int j = 0; j < 4; j++)
        for (int qh = 0; qh < 2; qh++) oacc[j][qh] = (f32x4){0.f, 0.f, 0.f, 0.f};
    lacc[0] = (f32x4){0.f, 0.f, 0.f, 0.f};
    lacc[1] = (f32x4){0.f, 0.f, 0.f, 0.f};

    // ---- K/V staging coords + swizzled write slots ----
    const int er = (tid * 8) >> 6;       // 0..31 (row; +32 for kreg1)
    const int ec = (tid * 8) & 63;       // 8-aligned col
    const int half_k = ec >> 5;          // col half
    const int chk_k  = (ec & 31) >> 3;   // 16B chunk within half (0..3)
    const int ks_s   = 4 * (er & 15) + chk_k;
    const int ks_z   = ks_s ^ ((ks_s >> 3) & 7);
    const int kw_r   = (er & ~15) + (ks_z >> 2);   // rows er / er+32 share sigma
    const int kw_c   = (ks_z & 3) * 8;

    const int dd = tid >> 2;             // 0..63 (V row)
    const int kg = tid & 3;
    const int half_v = kg >> 1;
    const int chv0 = 2 * (kg & 1);
    const int vs0 = 4 * (dd & 15) + chv0,     vz0 = vs0 ^ ((vs0 >> 3) & 7);
    const int vs1 = 4 * (dd & 15) + chv0 + 1, vz1 = vs1 ^ ((vs1 >> 3) & 7);
    const int vw_r0 = (dd & ~15) + (vz0 >> 2), vw_c0 = (vz0 & 3) * 8;
    const int vw_r1 = (dd & ~15) + (vz1 >> 2), vw_c1 = (vz1 & 3) * 8;

    // read side: logical (row lm in segment, chunk quad) -> sigma slot
    const int srd = 4 * lm + quad;
    const int srz = srd ^ ((srd >> 3) & 7);
    const int rsw = srz >> 2, csw = (srz & 3) * 8;

    short8 kreg0, kreg1, vreg0, vreg1;
    {
        kreg0 = *(const short8*)&k[base + (size_t)(er) * DIMC + ec];
        kreg1 = *(const short8*)&k[base + (size_t)(er + 32) * DIMC + ec];
        const size_t vsrc = vbase + (size_t)dd * SEQ + kg * 16;
        vreg0 = *(const short8*)&vt[vsrc];
        vreg1 = *(const short8*)&vt[vsrc + 8];
    }

    for (int kt = 0; kt < SEQ / 64; kt++) {
        __syncthreads();   // drains each wave's own ds_reads (qf / prior tiles)
        *(short8*)&Ks2[half_k][kw_r][kw_c]      = kreg0;
        *(short8*)&Ks2[half_k][kw_r + 32][kw_c] = kreg1;
        *(short8*)&Vt2[half_v][vw_r0][vw_c0]    = vreg0;
        *(short8*)&Vt2[half_v][vw_r1][vw_c1]    = vreg1;
        __syncthreads();
        if (kt + 1 < SEQ / 64) {
            const int kn = (kt + 1) * 64;
            kreg0 = *(const short8*)&k[base + (size_t)(kn + er) * DIMC + ec];
            kreg1 = *(const short8*)&k[base + (size_t)(kn + er + 32) * DIMC + ec];
            const size_t vsrc = vbase + (size_t)dd * SEQ + kn + kg * 16;
            vreg0 = *(const short8*)&vt[vsrc];
            vreg1 = *(const short8*)&vt[vsrc + 8];
        }

        f32x4 st[4][2];
        for (int j = 0; j < 4; j++)
            for (int qh = 0; qh < 2; qh++) st[j][qh] = (f32x4){0.f, 0.f, 0.f, 0.f};
        for (int ks = 0; ks < 2; ks++) {
            for (int j = 0; j < 4; j++) {
                short8 kf = *(const short8*)&Ks2[ks][j * 16 + rsw][csw];
                for (int qh = 0; qh < 2; qh++)
                    st[j][qh] = __builtin_amdgcn_mfma_f32_16x16x32_bf16(kf, qf[qh][ks], st[j][qh], 0, 0, 0);
            }
        }

        for (int j = 0; j < 4; j++)
            for (int qh = 0; qh < 2; qh++) {
                unsigned int u0 = __float_as_uint(__builtin_amdgcn_exp2f(st[j][qh][0]));
                unsigned int u1 = __float_as_uint(__builtin_amdgcn_exp2f(st[j][qh][1]));
                unsigned int u2 = __float_as_uint(__builtin_amdgcn_exp2f(st[j][qh][2]));
                unsigned int u3 = __float_as_uint(__builtin_amdgcn_exp2f(st[j][qh][3]));
                unsigned int lo = (u1 & 0xffff0000u) | (u0 >> 16);
                unsigned int hi = (u3 & 0xffff0000u) | (u2 >> 16);
                *(uint2*)&Ps[wave][qh * 16 + lm][j * 16 + quad * 4] = make_uint2(lo, hi);
            }

        for (int ks = 0; ks < 2; ks++) {
            for (int qh = 0; qh < 2; qh++) {
                short8 pf = *(const short8*)&Ps[wave][qh * 16 + lm][quad * 8 + ks * 32];
                lacc[qh] = __builtin_amdgcn_mfma_f32_16x16x32_bf16(pf, onef, lacc[qh], 0, 0, 0);
                for (int j = 0; j < 4; j++) {
                    short8 vf = *(const short8*)&Vt2[ks][j * 16 + rsw][csw];
                    oacc[j][qh] = __builtin_amdgcn_mfma_f32_16x16x32_bf16(pf, vf, oacc[j][qh], 0, 0, 0);
                }
            }
        }
    }

    float rinv[2][4];
    for (int qh = 0; qh < 2; qh++)
        for (int r = 0; r < 4; r++) rinv[qh][r] = 1.0f / fmaxf(lacc[qh][r], 1e-30f);

    for (int j = 0; j < 4; j++)
        for (int qh = 0; qh < 2; qh++)
            for (int r = 0; r < 4; r++) {
                const int row = q0 + wave * 32 + qh * 16 + quad * 4 + r;
                o[base + (size_t)row * DIMC + j * 16 + lm] = f2bf(oacc[j][qh][r] * rinv[qh][r]);
            }
}

// ---------------------------------------------------------------------------
extern "C" void kernel_launch(void* const* d_in, const int* in_sizes, int n_in,
                              void* d_out, int out_size, void* d_ws, size_t ws_size,
                              hipStream_t stream)
{
    const void* x   = d_in[0];
    const void* g1  = d_in[1];
    const void* b1  = d_in[2];
    const void* Wq  = d_in[3];
    const void* bq  = d_in[4];
    const void* Wk  = d_in[5];
    const void* bk  = d_in[6];
    const void* Wv  = d_in[7];
    const void* bv  = d_in[8];
    const void* Wo  = d_in[9];
    const void* bo  = d_in[10];
    const void* g2  = d_in[11];
    const void* b2  = d_in[12];
    const void* W1  = d_in[13];
    const void* bf1 = d_in[14];
    const void* W2  = d_in[15];
    const void* bf2 = d_in[16];

    const size_t SZ_TOKD_BF = (size_t)TOKENS * DIMC * 2;      //  8 MB
    const size_t SZ_TOKD_F  = (size_t)TOKENS * DIMC * 4;      // 16 MB
    const size_t SZ_W_SQ    = (size_t)DIMC * DIMC * 2;        //  2 MB
    const size_t SZ_W_FF    = (size_t)DIMC * HID * 2;         //  8 MB
    const size_t SZ_FF1     = (size_t)TOKENS * HID * 2;       // 32 MB

    char* ws = (char*)d_ws;
    size_t off = 0;
    int*      flag = (int*)(ws + off);       off += 256;
    ushort_t* h    = (ushort_t*)(ws + off);  off += SZ_TOKD_BF;
    ushort_t* qb   = (ushort_t*)(ws + off);  off += SZ_TOKD_BF;
    ushort_t* kb_  = (ushort_t*)(ws + off);  off += SZ_TOKD_BF;
    ushort_t* ao   = (ushort_t*)(ws + off);  off += SZ_TOKD_BF;  // attn out
    ushort_t* vtg  = (ushort_t*)(ws + off);  off += SZ_TOKD_BF;  // V transposed
    float*    x1f  = (float*)qb;             // 16MB over qb+kb (dead after attn)
    ushort_t* pa   = (ushort_t*)vtg;         // O-proj bf16 partial 0 (vtg dead after attn)
    ushort_t* p0   = (ushort_t*)ao;          // FF2 bf16 partial 0 (ao dead after O-proj)
    ushort_t* p2   = (ushort_t*)vtg;         // FF2 bf16 partial 2 (pa dead after reduce_ln)
    ushort_t* wqt  = (ushort_t*)(ws + off);  off += SZ_W_SQ;   // wq/wk/wv/wo CONTIGUOUS
    ushort_t* wkt  = (ushort_t*)(ws + off);  off += SZ_W_SQ;
    ushort_t* wvt  = (ushort_t*)(ws + off);  off += SZ_W_SQ;
    ushort_t* wot  = (ushort_t*)(ws + off);  off += SZ_W_SQ;
    ushort_t* w1t  = (ushort_t*)(ws + off);  off += SZ_W_FF;
    ushort_t* w2t  = (ushort_t*)(ws + off);  off += SZ_W_FF;
    ushort_t* ff1  = (ushort_t*)(ws + off);  off += SZ_FF1;
    ushort_t* p1   = (ushort_t*)(ws + off);  off += SZ_TOKD_F; // bf16 partial 1 (8MB used)
    ushort_t* p3   = (ushort_t*)wqt;         // FF2 bf16 partial 3 (wqt..wot 8MB, dead after O-proj/FF1)
    if (ws_size < off) return;   // insufficient workspace (output stays 0: diagnostic)

    (void)wkt; (void)wvt;

    detect_dtype<<<1, 256, 0, stream>>>((const ushort_t*)x, flag);

    // all weight transposes (+conversion) in one flat dispatch
    transpose_w_all<<<12288, 256, 0, stream>>>(Wq, Wk, Wv, Wo, W1, W2,
                                               wqt, w1t, w2t, flag);

    // LN1 (x raw, dtype per flag)
    ln_kernel<0><<<TOKENS, 256, 0, stream>>>(x, g1, b1, flag, h);

    // fused QKV projection: N=3072, BN=128, NBUF=3 (48KB -> 3/CU; 768 blocks
    // = EXACTLY one pass); V -> vtg transposed
    gemm_bt<128, 0, 0, 3, 3><<<dim3(24, 32), 256, 0, stream>>>(
        h, wqt, bq, bk, bv, nullptr, qb, kb_, vtg, TOKENS, 3072, DIMC, DIMC, flag);

    // attention -> ao (Q-tile 128; conflict-free K/V LDS)
    attn_kernel<<<dim3(32, 16), 256, 0, stream>>>(qb, kb_, vtg, ao);

    // O projection split-K=2, BN=64 -> bf16 partials pa(vtg) / p1
    gemm_bt<64, 0, 0, 4, 3><<<dim3(16, 32, 2), 256, 0, stream>>>(
        ao, wot, nullptr, nullptr, nullptr, nullptr, pa, p1, nullptr,
        TOKENS, DIMC, DIMC, DIMC / 2, flag);

    // FUSED: x1f = pa + p1 + bo + x (raw resid); h = LN(x1f; g2,b2)
    reduce_ln<<<TOKENS, 256, 0, stream>>>(
        pa, p1, bo, x, x1f, g2, b2, flag, h);

    // FF1 + GELU, BN=128 (1024 blocks; 48KB LDS -> 3/CU; 16 MFMA/step/wave)
    gemm_bt<128, 0, 1, 0, 3><<<dim3(32, 32), 256, 0, stream>>>(
        h, w1t, bf1, nullptr, nullptr, nullptr, ff1, nullptr, nullptr,
        TOKENS, HID, DIMC, DIMC, flag);

    // FF2 split-K=4, BN=128 (1024 blocks = 3/CU; 16 MFMA/step/wave)
    // bf16 partials: p0(ao) / p1 / p2(vtg) / p3(wqt..wot)
    gemm_bt<128, 0, 0, 4, 3><<<dim3(8, 32, 4), 256, 0, stream>>>(
        ff1, w2t, nullptr, nullptr, nullptr, p3, p0, p1, p2,
        TOKENS, DIMC, HID, HID / 4, flag);

    // reduce: d_out = cast(p0+p1+p2+p3 + bf2 + x1f), dtype per flag
    splitk4_reduce<<<TOKENS * DIMC / 1024, 256, 0, stream>>>(
        p0, p1, p2, p3, bf2, x1f, d_out, flag);
}